// Round 9
// baseline (97.444 us; speedup 1.0000x reference)
//
#include <hip/hip_runtime.h>

// NEAT windowed-DAG forward, R15: quad-split + 8-node regions + f16 + 2 waves/SIMD.
//   values[0:16] = x; for i in 0..511: v = tanh(dot(values[i:i+16], w[i]) + b[i]) * r[i]
//   out = values[T-64:T]
//
// Ledger (R6-R14): DS bytes null (R13), chain length null (R11), SMEM regress
// (R12), fence amortization -6% (R14). Never tested: low-issue structure at
// 2 waves/SIMD (R7/R8 had per-node fences + 2x issue; R9-R14 sat at 1 w/SIMD
// where ~90cyc of trans-dep/DPP-hazard residual is exposed in lockstep).
// This round: R7's plain quad-split taps (no injection -- proven worthless)
// + R13 f16 weights + R14 region fencing, at 8 waves/CU (block 512, grid 256).
// Issue ~56 cyc/node/SIMD, DS ~72 cyc/node/CU (new binder), fences /8.
// The co-resident wave fills chain/trans bubbles.
//
// u-domain (R8+ verified): u = sigmoid(-2z); w" = -2*kScale*w*rho (f16 RNE);
// Bq = kScale*(b + sum_j w*rho)/4 (f32, every lane's fma init; 4-lane DPP
// reduce restores B"). Inputs u=(1-x)/2; outputs o = rho*(1-2u).
//
// Window: lane jq of a quad holds taps (ages) 4jq..4jq+3 in regs r0..r3
// (role names rotate period 4; lane3's newest = u_{k-1} -> last fma of the
// lane-3 partial is the serial-chain op). Migration: vacated oldest reg
// pulls lane jq+1's oldest (quad_perm[1,2,3,0]); lane3 takes the new u.
//
// Region record (8 nodes, 384 B): weight pair m=0..3 at m*64: lane jq's
// b128 at +jq*16 = nodes {2m,2m+1} x 4 f16 (slots 4jq..4jq+3), node h at
// half h*8. Meta: Bq[s] chunks c=0..1 (4 nodes each) 4-way lane-replicated:
// replica jq of chunk c at 256 + c*64 + jq*16. Cursor a = base + 16*jq
// serves everything. 6 ds_read_b128/region, depth-1 dbuf, counted lgkmcnt(6).

typedef float    v4f __attribute__((ext_vector_type(4)));
typedef _Float16 h8  __attribute__((ext_vector_type(8)));

constexpr int   kNOut   = 64;
constexpr int   kBatch  = 32768;
constexpr int   kSgF    = 96;                     // floats per 8-node region (384 B)
constexpr int   kSgB    = 384;
constexpr int   kLdsFloats = 65 * kSgF;           // 64 regions + 1 pad (overrun)
constexpr float kScale  = 2.8853900817779268f;    // 2*log2(e)

// quad_perm DPP through the builtin so the compiler handles hazard nops.
#define QPERM(X, CTRL) __int_as_float(__builtin_amdgcn_update_dpp(            \
    __float_as_int(X), __float_as_int(X), (CTRL), 0xF, 0xF, false))

__device__ __forceinline__ unsigned pack2(float lo, float hi) {
    _Float16 l = (_Float16)lo, h = (_Float16)hi;    // RNE converts
    unsigned short ul = __builtin_bit_cast(unsigned short, l);
    unsigned short uh = __builtin_bit_cast(unsigned short, h);
    return ((unsigned)uh << 16) | ul;
}

// 6 ds_read_b128 for region set S: weight pairs m=0..3 + meta chunks c=0..1.
// All addresses are 4-way (one per jq) -> bank-disjoint broadcast.
#define PREF(S) {                                                             \
    asm volatile(                                                             \
      "ds_read_b128 %0, %6 offset:0\n\t"                                      \
      "ds_read_b128 %1, %6 offset:64\n\t"                                     \
      "ds_read_b128 %2, %6 offset:128\n\t"                                    \
      "ds_read_b128 %3, %6 offset:192\n\t"                                    \
      "ds_read_b128 %4, %6 offset:256\n\t"                                    \
      "ds_read_b128 %5, %6 offset:320"                                        \
      : "=&v"(qw0[S]), "=&v"(qw1[S]), "=&v"(qw2[S]), "=&v"(qw3[S]),           \
        "=&v"(qm0[S]), "=&v"(qm1[S])                                          \
      : "v"(a));                                                              \
    a += kSgB; }

// Depth-1 dbuf: waiting for set S, only the other set's 6 reads are newer;
// in-order DS returns make lgkmcnt(6) == "set S landed". "+v" ties the
// consumers to this asm (proven R6-R14 pattern).
#define WAITR(S)                                                              \
    asm volatile("s_waitcnt lgkmcnt(6)"                                       \
      : "+v"(qw0[S]), "+v"(qw1[S]), "+v"(qw2[S]), "+v"(qw3[S]),               \
        "+v"(qm0[S]), "+v"(qm1[S]));

// One node. WPAIR = weight b128 (2 nodes), H = node half (0/1). BQ = B"/4.
// A0..A3 = lane's taps oldest->newest (lane3's A3 = u_{k-1}: chain).
// Reduce: 2 quad DPP stages; all lanes get the full sum (incl. 4x Bq).
// Migration: A0 <- lane jq+1's A0 (quad_perm[1,2,3,0]); lane3 <- new u.
#define NODE(WPAIR, H, BQ, A0,A1,A2,A3) {                                     \
    h8 wh = __builtin_bit_cast(h8, (WPAIR));                                  \
    float p = fmaf((A0), (float)wh[4*(H)+0], (BQ));                           \
    p = fmaf((A1), (float)wh[4*(H)+1], p);                                    \
    p = fmaf((A2), (float)wh[4*(H)+2], p);                                    \
    p = fmaf((A3), (float)wh[4*(H)+3], p);                                    \
    float s1 = p + QPERM(p, 0xB1);          /* quad_perm:[1,0,3,2] */         \
    float s2 = s1 + QPERM(s1, 0x4E);        /* quad_perm:[2,3,0,1] */         \
    float mg = QPERM((A0), 0x39);           /* quad_perm:[1,2,3,0] */         \
    float ex = __builtin_amdgcn_exp2f(s2);                                    \
    float un = __builtin_amdgcn_rcpf(ex + 1.0f);                              \
    (A0) = is_l3 ? un : mg; }

// 8-node region: one prefetch (other set), one counted wait, 8 nodes.
// Role names rotate period 4 -> realigned after 8 nodes.
#define REGION(SP, SC) {                                                      \
    PREF(SP)                                                                  \
    WAITR(SC)                                                                 \
    NODE(qw0[SC], 0, qm0[SC].x, r0,r1,r2,r3)                                  \
    NODE(qw0[SC], 1, qm0[SC].y, r1,r2,r3,r0)                                  \
    NODE(qw1[SC], 0, qm0[SC].z, r2,r3,r0,r1)                                  \
    NODE(qw1[SC], 1, qm0[SC].w, r3,r0,r1,r2)                                  \
    NODE(qw2[SC], 0, qm1[SC].x, r0,r1,r2,r3)                                  \
    NODE(qw2[SC], 1, qm1[SC].y, r1,r2,r3,r0)                                  \
    NODE(qw3[SC], 0, qm1[SC].z, r2,r3,r0,r1)                                  \
    NODE(qw3[SC], 1, qm1[SC].w, r3,r0,r1,r2) }

__global__ __launch_bounds__(512) void neat_fwd(
    const float* __restrict__ x,      // [B, 16]
    const float* __restrict__ w,      // [512, 16]
    const float* __restrict__ bias,   // [512]
    const float* __restrict__ resp,   // [512]
    float* __restrict__ out)          // [B, 64]
{
    __shared__ alignas(16) float ldsw[kLdsFloats];
    __shared__ float rst[512];

    const int t  = threadIdx.x;       // 0..511 (8 waves)
    const int jq = t & 3;             // lane within quad
    const bool is_l3 = (jq == 3);

    // ---- Stage: raw resp ----
    rst[t] = resp[t];
    __syncthreads();

    // ---- Stage node n = t ----
    {
        const int n = t;
        const float4* wn = reinterpret_cast<const float4*>(w) + n * 4;
        float4 a0 = wn[0], a1 = wn[1], a2 = wn[2], a3 = wn[3];
        const float m2k = -2.0f * kScale;
        float sum = 0.0f;
        float ws0,ws1,ws2,ws3,ws4,ws5,ws6,ws7,ws8,ws9,ws10,ws11,ws12,ws13,ws14,ws15;
        #define DO(J, V) { float rho = (n + (J) < 16) ? 1.0f : rst[n + (J) - 16]; \
                           float wr = (V) * rho; sum += wr; ws##J = wr * m2k; }
        DO(0,a0.x)  DO(1,a0.y)  DO(2,a0.z)  DO(3,a0.w)
        DO(4,a1.x)  DO(5,a1.y)  DO(6,a1.z)  DO(7,a1.w)
        DO(8,a2.x)  DO(9,a2.y)  DO(10,a2.z) DO(11,a2.w)
        DO(12,a3.x) DO(13,a3.y) DO(14,a3.z) DO(15,a3.w)
        #undef DO
        const int sg = n >> 3, s = n & 7, m = s >> 1, h = s & 1;
        // weights: lane-block jq at sg*384 + m*64 + jq*16, node half h*8
        unsigned* lu = reinterpret_cast<unsigned*>(ldsw);
        int wi = sg * 96 + m * 16 + h * 2;          // u32 index (jq term below)
        lu[wi + 0*4 + 0] = pack2(ws0,  ws1);   lu[wi + 0*4 + 1] = pack2(ws2,  ws3);
        lu[wi + 1*4 + 0] = pack2(ws4,  ws5);   lu[wi + 1*4 + 1] = pack2(ws6,  ws7);
        lu[wi + 2*4 + 0] = pack2(ws8,  ws9);   lu[wi + 2*4 + 1] = pack2(ws10, ws11);
        lu[wi + 3*4 + 0] = pack2(ws12, ws13);  lu[wi + 3*4 + 1] = pack2(ws14, ws15);
        // meta: Bq chunks c=s>>2 pos p=s&3, replicas r=0..3
        float Bq = (bias[n] + sum) * (kScale * 0.25f);
        const int c = s >> 2, p = s & 3;
        int mi = sg * 96 + 64 + c * 16 + p;
        ldsw[mi + 0]  = Bq;
        ldsw[mi + 4]  = Bq;
        ldsw[mi + 8]  = Bq;
        ldsw[mi + 12] = Bq;
    }

    // ---- Per-thread window init: lane jq holds enc(x_{4jq..4jq+3}) ----
    const int e = blockIdx.x * 128 + (t >> 2);     // batch element
    const float4 xi = reinterpret_cast<const float4*>(x)[e * 4 + jq];
    float r0 = fmaf(-0.5f, xi.x, 0.5f);    // u = (1-x)/2 (exact affine)
    float r1 = fmaf(-0.5f, xi.y, 0.5f);
    float r2 = fmaf(-0.5f, xi.z, 0.5f);
    float r3 = fmaf(-0.5f, xi.w, 0.5f);

    const float4* __restrict__ rr4 = reinterpret_cast<const float4*>(resp);
    float* __restrict__ op = out + (size_t)e * kNOut + jq * 4;

    __syncthreads();   // drains staging ds ops (compiler lgkmcnt(0))

    // DS byte cursor (+ lane's 16B block offset folded in).
    unsigned int a = (unsigned int)(unsigned long long)(&ldsw[0])
                   + (unsigned int)(jq << 4);

    v4f qw0[2], qw1[2], qw2[2], qw3[2], qm0[2], qm1[2];
    PREF(0)                       // region 0 in flight

    #pragma unroll 1
    for (int g = 0; g < 32; ++g) {
        REGION(1, 0)              // prefetch next 8 nodes, compute current 8
        REGION(0, 1)
        // After 16 nodes: lane jq's r_c = u_{16g + 4jq + c}.
        if (g >= 28) {
            const int m_ = g - 28;
            const float4 rv = rr4[112 + 4 * m_ + jq];
            *reinterpret_cast<float4*>(op + 16 * m_) =
                make_float4(fmaf(-2.0f, r0, 1.0f) * rv.x,
                            fmaf(-2.0f, r1, 1.0f) * rv.y,
                            fmaf(-2.0f, r2, 1.0f) * rv.z,
                            fmaf(-2.0f, r3, 1.0f) * rv.w);
        }
    }

    // Drain the overrun prefetch (pad region 64).
    asm volatile("s_waitcnt lgkmcnt(0)" ::: "memory");
}

extern "C" void kernel_launch(void* const* d_in, const int* in_sizes, int n_in,
                              void* d_out, int out_size, void* d_ws, size_t ws_size,
                              hipStream_t stream) {
    const float* x    = (const float*)d_in[0];
    const float* w    = (const float*)d_in[1];
    const float* bias = (const float*)d_in[2];
    const float* resp = (const float*)d_in[3];
    float* out = (float*)d_out;
    // in_sizes[4] (src_idx) encodes the fixed windowed topology; hardcoded above.
    dim3 block(512);
    dim3 grid(kBatch * 4 / 512);   // 256 blocks -> 1/CU, 8 waves/CU = 2 per SIMD
    hipLaunchKernelGGL(neat_fwd, grid, block, 0, stream, x, w, bias, resp, out);
}